// Round 1
// baseline (3066.599 us; speedup 1.0000x reference)
//
#include <hip/hip_runtime.h>

#define HH 256
#define WW 256
#define SS 65536   // pixels per mask; also the background sentinel label
#define NM 128     // B*K masks

struct Meta {
  double dsum[NM];    // total sum of m per mask
  double dloss[NM];   // per-mask loss
  int fgcnt[NM];
  int second[NM];     // second-largest-area label (0..SS)
  int h0[NM]; int h1[NM]; int w0[NM]; int w1[NM];  // bbox (h1,w1 inclusive)
};

__global__ void k_meta_init(Meta* mt) {
  int i = threadIdx.x;
  if (i < NM) {
    mt->dsum[i] = 0.0; mt->dloss[i] = 0.0;
    mt->fgcnt[i] = 0;  mt->second[i] = -1;
    mt->h0[i] = HH; mt->h1[i] = -1; mt->w0[i] = WW; mt->w1[i] = -1;
  }
}

// One block = one 256-pixel row of one mask (65536 % 256 == 0).
__global__ void k_init(const float* __restrict__ in, int c0,
                       int* __restrict__ labels, int* __restrict__ areas,
                       Meta* __restrict__ mt) {
  int p    = blockIdx.x * blockDim.x + threadIdx.x;  // chunk-local pixel
  int lm   = p >> 16;                                // chunk-local mask
  int lidx = p & 0xFFFF;                             // pixel index in mask
  int gm   = c0 + lm;
  float x = in[(size_t)gm * SS + lidx];
  float m = fmaxf((x + 1.0f) * 0.5f, 0.0f);          // same expr as reference
  bool fg = m > 0.5f;
  labels[p] = fg ? lidx : SS;
  areas[p]  = 0;
  __shared__ double sd[256];
  sd[threadIdx.x] = (double)m;
  __syncthreads();
  for (int off = 128; off > 0; off >>= 1) {
    if (threadIdx.x < off) sd[threadIdx.x] += sd[threadIdx.x + off];
    __syncthreads();
  }
  if (threadIdx.x == 0) atomicAdd(&mt->dsum[gm], sd[0]);
}

__device__ __forceinline__ int find_root(int* L, int x) {
  int p = L[x];
  while (p != x) { x = p; p = L[x]; }
  return x;
}

// Komura-style union: always link larger root -> smaller root, so the final
// root is the component's minimum pixel index (matches reference labels).
__device__ void unite(int* L, int a, int b) {
  bool done = false;
  do {
    a = find_root(L, a);
    b = find_root(L, b);
    if (a < b)      { int old = atomicMin(&L[b], a); done = (old == b); b = old; }
    else if (b < a) { int old = atomicMin(&L[a], b); done = (old == a); a = old; }
    else done = true;
  } while (!done);
}

__global__ void k_merge(int* __restrict__ labels) {
  int p    = blockIdx.x * blockDim.x + threadIdx.x;
  int lm   = p >> 16;
  int lidx = p & 0xFFFF;
  int* L   = labels + ((size_t)lm << 16);
  if (L[lidx] == SS) return;  // background (fg labels only ever decrease)
  int r = lidx >> 8, c = lidx & 0xFF;
  // prior 8-neighbors: W, NW, N, NE — covers every 8-connected pair once
  if (c > 0 && L[lidx - 1] != SS) unite(L, lidx, lidx - 1);
  if (r > 0) {
    if (c > 0      && L[lidx - WW - 1] != SS) unite(L, lidx, lidx - WW - 1);
    if (             L[lidx - WW]     != SS) unite(L, lidx, lidx - WW);
    if (c < WW - 1 && L[lidx - WW + 1] != SS) unite(L, lidx, lidx - WW + 1);
  }
}

__global__ void k_flatten(int* __restrict__ labels, int* __restrict__ areas,
                          Meta* __restrict__ mt, int c0) {
  int p    = blockIdx.x * blockDim.x + threadIdx.x;
  int lm   = p >> 16;
  int lidx = p & 0xFFFF;
  int* L   = labels + ((size_t)lm << 16);
  int v = L[lidx];
  int isfg = (v != SS) ? 1 : 0;
  if (isfg) {
    int r = find_root(L, lidx);
    L[lidx] = r;  // concurrent path compression to a static root: safe
    atomicAdd(&areas[(lm << 16) + r], 1);
  }
  __shared__ int sc[256];
  sc[threadIdx.x] = isfg;
  __syncthreads();
  for (int off = 128; off > 0; off >>= 1) {
    if (threadIdx.x < off) sc[threadIdx.x] += sc[threadIdx.x + off];
    __syncthreads();
  }
  if (threadIdx.x == 0) atomicAdd(&mt->fgcnt[c0 + lm], sc[0]);
}

// key = (area << 17) | (SS - label): max key == (area desc, label asc) — the
// exact lax.top_k ordering. All keys distinct (distinct labels).
__global__ void k_top2(const int* __restrict__ areas, Meta* __restrict__ mt,
                       int c0) {
  int lm = blockIdx.x;
  int gm = c0 + lm;
  const int* A = areas + ((size_t)lm << 16);
  unsigned long long t1 = 0, t2 = 0;
  for (int i = threadIdx.x; i < SS; i += blockDim.x) {
    unsigned long long key =
        ((unsigned long long)A[i] << 17) | (unsigned)(SS - i);
    if (key > t1) { t2 = t1; t1 = key; }
    else if (key > t2) { t2 = key; }
  }
  if (threadIdx.x == 0) {  // background label SS, area = SS - fgcnt
    unsigned long long key =
        ((unsigned long long)(SS - mt->fgcnt[gm]) << 17);  // (SS - SS) == 0
    if (key > t1) { t2 = t1; t1 = key; }
    else if (key > t2) { t2 = key; }
  }
  __shared__ unsigned long long s1[256], s2[256];
  s1[threadIdx.x] = t1; s2[threadIdx.x] = t2;
  __syncthreads();
  for (int off = 128; off > 0; off >>= 1) {
    if (threadIdx.x < off) {
      unsigned long long a1 = s1[threadIdx.x], a2 = s2[threadIdx.x];
      unsigned long long b1 = s1[threadIdx.x + off], b2 = s2[threadIdx.x + off];
      if (b1 > a1) { a2 = (a1 > b2) ? a1 : b2; a1 = b1; }
      else         { a2 = (a2 > b1) ? a2 : b1; }
      s1[threadIdx.x] = a1; s2[threadIdx.x] = a2;
    }
    __syncthreads();
  }
  if (threadIdx.x == 0) mt->second[gm] = SS - (int)(s2[0] & 0x1FFFF);
}

// One block = one row: per-row col min/max reduce, then 4 atomics per row.
__global__ void k_bbox(const int* __restrict__ labels, Meta* __restrict__ mt,
                       int c0) {
  int p    = blockIdx.x * blockDim.x + threadIdx.x;
  int lm   = p >> 16;
  int lidx = p & 0xFFFF;
  int gm   = c0 + lm;
  int sec  = mt->second[gm];
  int lab  = labels[p];
  int r = lidx >> 8, c = lidx & 0xFF;
  bool sel = (lab == sec);
  __shared__ int smn[256], smx[256];
  smn[threadIdx.x] = sel ? c : WW;
  smx[threadIdx.x] = sel ? c : -1;
  __syncthreads();
  for (int off = 128; off > 0; off >>= 1) {
    if (threadIdx.x < off) {
      smn[threadIdx.x] = min(smn[threadIdx.x], smn[threadIdx.x + off]);
      smx[threadIdx.x] = max(smx[threadIdx.x], smx[threadIdx.x + off]);
    }
    __syncthreads();
  }
  if (threadIdx.x == 0 && smx[0] >= 0) {
    atomicMin(&mt->w0[gm], smn[0]);
    atomicMax(&mt->w1[gm], smx[0]);
    atomicMin(&mt->h0[gm], r);
    atomicMax(&mt->h1[gm], r);
  }
}

// One block per mask: sum m over the (inclusive) bbox, finish per-mask loss.
__global__ void k_inside(const float* __restrict__ in, Meta* __restrict__ mt,
                         int c0) {
  int lm = blockIdx.x;
  int gm = c0 + lm;
  int h0 = mt->h0[gm], h1 = mt->h1[gm], w0 = mt->w0[gm], w1 = mt->w1[gm];
  double acc = 0.0;
  if (h1 >= h0) {
    int bw = w1 - w0 + 1;
    int tot = bw * (h1 - h0 + 1);
    const float* base = in + (size_t)gm * SS;
    for (int i = threadIdx.x; i < tot; i += blockDim.x) {
      int rr = h0 + i / bw, cc = w0 + i % bw;
      float x = base[rr * WW + cc];
      acc += (double)fmaxf((x + 1.0f) * 0.5f, 0.0f);
    }
  }
  __shared__ double sd[256];
  sd[threadIdx.x] = acc;
  __syncthreads();
  for (int off = 128; off > 0; off >>= 1) {
    if (threadIdx.x < off) sd[threadIdx.x] += sd[threadIdx.x + off];
    __syncthreads();
  }
  if (threadIdx.x == 0)
    mt->dloss[gm] = (mt->dsum[gm] - sd[0]) / (double)SS;
}

__global__ void k_final(const Meta* __restrict__ mt, float* __restrict__ out) {
  __shared__ double sd[NM];
  int t = threadIdx.x;
  sd[t] = mt->dloss[t];
  __syncthreads();
  for (int off = 64; off > 0; off >>= 1) {
    if (t < off) sd[t] += sd[t + off];
    __syncthreads();
  }
  if (t == 0) out[0] = (float)(sd[0] / (double)NM);
}

extern "C" void kernel_launch(void* const* d_in, const int* in_sizes, int n_in,
                              void* d_out, int out_size, void* d_ws,
                              size_t ws_size, hipStream_t stream) {
  const float* in = (const float*)d_in[0];
  float* out = (float*)d_out;

  Meta* mt = (Meta*)d_ws;
  const size_t meta_bytes = (sizeof(Meta) + 255) & ~(size_t)255;
  char* base = (char*)d_ws + meta_bytes;
  size_t avail = (ws_size > meta_bytes) ? (ws_size - meta_bytes) : 0;
  int chunk = (int)(avail / (2ull * SS * sizeof(int)));  // labels + areas
  if (chunk > NM) chunk = NM;
  if (chunk < 1) return;  // insufficient workspace (would fail validation)

  int* labels = (int*)base;
  int* areas  = labels + (size_t)chunk * SS;

  k_meta_init<<<1, 128, 0, stream>>>(mt);
  for (int c0 = 0; c0 < NM; c0 += chunk) {
    int cn = (chunk < NM - c0) ? chunk : (NM - c0);
    int blocks = cn * (SS / 256);
    k_init   <<<blocks, 256, 0, stream>>>(in, c0, labels, areas, mt);
    k_merge  <<<blocks, 256, 0, stream>>>(labels);
    k_flatten<<<blocks, 256, 0, stream>>>(labels, areas, mt, c0);
    k_top2   <<<cn,     256, 0, stream>>>(areas, mt, c0);
    k_bbox   <<<blocks, 256, 0, stream>>>(labels, mt, c0);
    k_inside <<<cn,     256, 0, stream>>>(in, mt, c0);
  }
  k_final<<<1, 128, 0, stream>>>(mt, out);
}

// Round 2
// 1093.972 us; speedup vs baseline: 2.8032x; 2.8032x over previous
//
#include <hip/hip_runtime.h>

#define HH 256
#define WW 256
#define SS 65536   // pixels per mask; also the background sentinel label
#define NM 128     // B*K masks

struct Meta {
  double dsum[NM];    // total sum of m per mask
  double dloss[NM];   // per-mask loss
  int second[NM];     // second-largest-area label (0..SS)
  int h0[NM]; int h1[NM]; int w0[NM]; int w1[NM];  // bbox (inclusive h1,w1)
};

__global__ void k_meta_init(Meta* mt) {
  int i = threadIdx.x;
  if (i < NM) {
    mt->dsum[i] = 0.0; mt->dloss[i] = 0.0; mt->second[i] = -1;
    mt->h0[i] = HH; mt->h1[i] = -1; mt->w0[i] = WW; mt->w1[i] = -1;
  }
}

// One block = one 256-px row. Run-based init: each fg pixel's label = index of
// the start of its horizontal fg-run (computed by an LDS max-scan). This makes
// intra-row chains depth-0 and eliminates all W-neighbor unions in k_merge.
__global__ void k_init(const float* __restrict__ in, int c0,
                       int* __restrict__ labels, int* __restrict__ areas,
                       Meta* __restrict__ mt) {
  int row  = blockIdx.x;        // chunk-local row id = lm*256 + r
  int lm   = row >> 8;
  int r    = row & 0xFF;
  int c    = threadIdx.x;
  int lidx = (r << 8) | c;
  int gm   = c0 + lm;
  int p    = (lm << 16) | lidx;

  float x = in[(size_t)gm * SS + lidx];
  float m = fmaxf((x + 1.0f) * 0.5f, 0.0f);   // same expr as reference
  bool fg = m > 0.5f;

  __shared__ unsigned char sfg[256];
  __shared__ int    sval[256];
  __shared__ double sd[256];
  sfg[c] = fg ? 1 : 0;
  sd[c]  = (double)m;
  __syncthreads();

  // v = run-start candidates; inclusive max-scan gives each fg pixel the
  // largest run-start index <= c, i.e. the start of its own run.
  int v = (fg && (c == 0 || !sfg[c - 1])) ? lidx : -1;
  sval[c] = v;
  __syncthreads();
  for (int off = 1; off < 256; off <<= 1) {
    int t = (c >= off) ? sval[c - off] : -1;
    __syncthreads();
    if (t > sval[c]) sval[c] = t;
    __syncthreads();
  }
  labels[p] = fg ? sval[c] : SS;
  areas[p]  = 0;

  for (int off = 128; off > 0; off >>= 1) {
    if (c < off) sd[c] += sd[c + off];
    __syncthreads();
  }
  if (c == 0) atomicAdd(&mt->dsum[gm], sd[0]);
}

__device__ __forceinline__ int find_root(int* L, int x) {
  int p = L[x];
  while (p != x) { x = p; p = L[x]; }
  return x;
}

// Komura-style union: always link larger root -> smaller root, so the final
// root is the component's minimum pixel index (matches reference labels).
__device__ void unite(int* L, int a, int b) {
  bool done = false;
  do {
    a = find_root(L, a);
    b = find_root(L, b);
    if (a < b)      { int old = atomicMin(&L[b], a); done = (old == b); b = old; }
    else if (b < a) { int old = atomicMin(&L[a], b); done = (old == a); a = old; }
    else done = true;
  } while (!done);
}

// Vertical-only unions. If N is fg, NW/NE (when fg) belong to N's run (they're
// horizontally adjacent to N), so a single unite with N covers all three.
__global__ void k_merge(int* __restrict__ labels) {
  int p    = blockIdx.x * blockDim.x + threadIdx.x;
  int lm   = p >> 16;
  int lidx = p & 0xFFFF;
  int* L   = labels + ((size_t)lm << 16);
  int v = L[lidx];
  if (v == SS) return;
  int r = lidx >> 8, c = lidx & 0xFF;
  if (r == 0) return;
  int n = L[lidx - WW];
  if (n != SS) { unite(L, v, n); return; }
  if (c > 0) {
    int nw = L[lidx - WW - 1];
    if (nw != SS) unite(L, v, nw);
  }
  if (c < WW - 1) {
    int ne = L[lidx - WW + 1];
    if (ne != SS) unite(L, v, ne);
  }
}

// Path-halving find. Safe post-merge: the union tree is static, every store
// writes a valid ancestor; racing stores only lose some compression.
__device__ __forceinline__ int find_halve(int* L, int x) {
  int p = L[x];
  while (p != x) {
    int gp = L[p];
    if (gp == p) return p;
    L[x] = gp;
    x = p; p = gp;
  }
  return x;
}

__global__ void k_flatten(int* __restrict__ labels, int* __restrict__ areas) {
  int p    = blockIdx.x * blockDim.x + threadIdx.x;
  int lm   = p >> 16;
  int lidx = p & 0xFFFF;
  int* L   = labels + ((size_t)lm << 16);
  int v = L[lidx];
  bool isfg = (v != SS);
  int rt = SS;
  if (isfg) {
    rt = find_halve(L, v);
    L[lidx] = rt;
  }
  // Wave-aggregated per-root area counting: one atomic per distinct root per
  // wave (consecutive lanes are consecutive pixels -> usually 1-3 roots).
  int lane = threadIdx.x & 63;
  bool pending = isfg;
  while (__any(pending)) {
    unsigned long long mask = __ballot(pending);
    int src  = __ffsll(mask) - 1;
    int lead = __shfl(rt, src);
    bool mine = pending && (rt == lead);
    unsigned long long grp = __ballot(mine);
    if (lane == src)
      atomicAdd(&areas[(lm << 16) + lead], (int)__popcll(grp));
    pending = pending && !mine;
  }
}

// key = (area << 17) | (SS - label): max key == (area desc, label asc) — the
// exact lax.top_k ordering. Background area derived from sum(areas) inline.
__global__ void k_top2(const int* __restrict__ areas, Meta* __restrict__ mt,
                       int c0) {
  int lm = blockIdx.x;
  int gm = c0 + lm;
  const int* A = areas + ((size_t)lm << 16);
  unsigned long long t1 = 0, t2 = 0;
  int mysum = 0;
  for (int i = threadIdx.x; i < SS; i += blockDim.x) {
    int a = A[i];
    mysum += a;
    unsigned long long key =
        ((unsigned long long)a << 17) | (unsigned)(SS - i);
    if (key > t1) { t2 = t1; t1 = key; }
    else if (key > t2) { t2 = key; }
  }
  __shared__ unsigned long long s1[1024], s2[1024];
  __shared__ int ssum[1024];
  s1[threadIdx.x] = t1; s2[threadIdx.x] = t2; ssum[threadIdx.x] = mysum;
  __syncthreads();
  for (int off = blockDim.x >> 1; off > 0; off >>= 1) {
    if (threadIdx.x < off) {
      unsigned long long a1 = s1[threadIdx.x], a2 = s2[threadIdx.x];
      unsigned long long b1 = s1[threadIdx.x + off], b2 = s2[threadIdx.x + off];
      if (b1 > a1) { a2 = (a1 > b2) ? a1 : b2; a1 = b1; }
      else         { a2 = (a2 > b1) ? a2 : b1; }
      s1[threadIdx.x] = a1; s2[threadIdx.x] = a2;
      ssum[threadIdx.x] += ssum[threadIdx.x + off];
    }
    __syncthreads();
  }
  if (threadIdx.x == 0) {
    // background: label SS, area = SS - fgcnt, low bits (SS - SS) == 0
    unsigned long long bk = ((unsigned long long)(SS - ssum[0]) << 17);
    unsigned long long a1 = s1[0], a2 = s2[0];
    if (bk > a1) { a2 = a1; a1 = bk; }
    else if (bk > a2) { a2 = bk; }
    mt->second[gm] = SS - (int)(a2 & 0x1FFFF);
  }
}

// One block = one row: per-row col min/max reduce, then 4 atomics per row.
__global__ void k_bbox(const int* __restrict__ labels, Meta* __restrict__ mt,
                       int c0) {
  int p    = blockIdx.x * blockDim.x + threadIdx.x;
  int lm   = p >> 16;
  int lidx = p & 0xFFFF;
  int gm   = c0 + lm;
  int sec  = mt->second[gm];
  int lab  = labels[p];
  int r = lidx >> 8, c = lidx & 0xFF;
  bool sel = (lab == sec);
  __shared__ int smn[256], smx[256];
  smn[threadIdx.x] = sel ? c : WW;
  smx[threadIdx.x] = sel ? c : -1;
  __syncthreads();
  for (int off = 128; off > 0; off >>= 1) {
    if (threadIdx.x < off) {
      smn[threadIdx.x] = min(smn[threadIdx.x], smn[threadIdx.x + off]);
      smx[threadIdx.x] = max(smx[threadIdx.x], smx[threadIdx.x + off]);
    }
    __syncthreads();
  }
  if (threadIdx.x == 0 && smx[0] >= 0) {
    atomicMin(&mt->w0[gm], smn[0]);
    atomicMax(&mt->w1[gm], smx[0]);
    atomicMin(&mt->h0[gm], r);
    atomicMax(&mt->h1[gm], r);
  }
}

// One block per mask: sum m over the (inclusive) bbox, finish per-mask loss.
__global__ void k_inside(const float* __restrict__ in, Meta* __restrict__ mt,
                         int c0) {
  int lm = blockIdx.x;
  int gm = c0 + lm;
  int h0 = mt->h0[gm], h1 = mt->h1[gm], w0 = mt->w0[gm], w1 = mt->w1[gm];
  double acc = 0.0;
  if (h1 >= h0) {
    int bw  = w1 - w0 + 1;
    int tot = bw * (h1 - h0 + 1);
    const float* base = in + (size_t)gm * SS;
    for (int i = threadIdx.x; i < tot; i += blockDim.x) {
      int rr = h0 + i / bw, cc = w0 + i % bw;
      float x = base[rr * WW + cc];
      acc += (double)fmaxf((x + 1.0f) * 0.5f, 0.0f);
    }
  }
  __shared__ double sd[512];
  sd[threadIdx.x] = acc;
  __syncthreads();
  for (int off = (int)blockDim.x >> 1; off > 0; off >>= 1) {
    if (threadIdx.x < off) sd[threadIdx.x] += sd[threadIdx.x + off];
    __syncthreads();
  }
  if (threadIdx.x == 0)
    mt->dloss[gm] = (mt->dsum[gm] - sd[0]) / (double)SS;
}

__global__ void k_final(const Meta* __restrict__ mt, float* __restrict__ out) {
  __shared__ double sd[NM];
  int t = threadIdx.x;
  sd[t] = mt->dloss[t];
  __syncthreads();
  for (int off = 64; off > 0; off >>= 1) {
    if (t < off) sd[t] += sd[t + off];
    __syncthreads();
  }
  if (t == 0) out[0] = (float)(sd[0] / (double)NM);
}

extern "C" void kernel_launch(void* const* d_in, const int* in_sizes, int n_in,
                              void* d_out, int out_size, void* d_ws,
                              size_t ws_size, hipStream_t stream) {
  const float* in = (const float*)d_in[0];
  float* out = (float*)d_out;

  Meta* mt = (Meta*)d_ws;
  const size_t meta_bytes = (sizeof(Meta) + 255) & ~(size_t)255;
  char* base = (char*)d_ws + meta_bytes;
  size_t avail = (ws_size > meta_bytes) ? (ws_size - meta_bytes) : 0;
  int chunk = (int)(avail / (2ull * SS * sizeof(int)));  // labels + areas
  if (chunk > NM) chunk = NM;
  if (chunk < 1) return;  // insufficient workspace (would fail validation)

  int* labels = (int*)base;
  int* areas  = labels + (size_t)chunk * SS;

  k_meta_init<<<1, 128, 0, stream>>>(mt);
  for (int c0 = 0; c0 < NM; c0 += chunk) {
    int cn = (chunk < NM - c0) ? chunk : (NM - c0);
    int blocks = cn * (SS / 256);
    k_init   <<<blocks, 256, 0, stream>>>(in, c0, labels, areas, mt);
    k_merge  <<<blocks, 256, 0, stream>>>(labels);
    k_flatten<<<blocks, 256, 0, stream>>>(labels, areas);
    k_top2   <<<cn,    1024, 0, stream>>>(areas, mt, c0);
    k_bbox   <<<blocks, 256, 0, stream>>>(labels, mt, c0);
    k_inside <<<cn,     512, 0, stream>>>(in, mt, c0);
  }
  k_final<<<1, 128, 0, stream>>>(mt, out);
}

// Round 3
// 890.233 us; speedup vs baseline: 3.4447x; 1.2289x over previous
//
#include <hip/hip_runtime.h>

#define HH 256
#define WW 256
#define SS 65536   // pixels per mask; also the background sentinel label
#define NM 128     // B*K masks

struct Meta {
  double dsum[NM];    // total sum of m per mask
  double dloss[NM];   // per-mask loss
  int second[NM];     // second-largest-area label (0..SS)
  int h0[NM]; int h1[NM]; int w0[NM]; int w1[NM];  // bbox (inclusive h1,w1)
};

__global__ void k_meta_init(Meta* mt) {
  int i = threadIdx.x;
  if (i < NM) {
    mt->dsum[i] = 0.0; mt->dloss[i] = 0.0; mt->second[i] = -1;
    mt->h0[i] = HH; mt->h1[i] = -1; mt->w0[i] = WW; mt->w1[i] = -1;
  }
}

// One block = one 256-px row. Run-based init: each fg pixel's label = index of
// the start of its horizontal fg-run (LDS max-scan). Only run-start entries of
// `areas` are zeroed (they're the only atomicAdd targets; k_top2 gates on
// roots, so other entries are never read).
__global__ void k_init(const float* __restrict__ in, int c0,
                       int* __restrict__ labels, int* __restrict__ areas,
                       Meta* __restrict__ mt) {
  int row  = blockIdx.x;        // chunk-local row id = lm*256 + r
  int lm   = row >> 8;
  int r    = row & 0xFF;
  int c    = threadIdx.x;
  int lidx = (r << 8) | c;
  int gm   = c0 + lm;
  int p    = (lm << 16) | lidx;

  float x = in[(size_t)gm * SS + lidx];
  float m = fmaxf((x + 1.0f) * 0.5f, 0.0f);   // same expr as reference
  bool fg = m > 0.5f;

  __shared__ unsigned char sfg[256];
  __shared__ int    sval[256];
  __shared__ double sd[256];
  sfg[c] = fg ? 1 : 0;
  sd[c]  = (double)m;
  __syncthreads();

  bool rs = fg && (c == 0 || !sfg[c - 1]);   // run start
  int v = rs ? lidx : -1;
  sval[c] = v;
  __syncthreads();
  for (int off = 1; off < 256; off <<= 1) {
    int t = (c >= off) ? sval[c - off] : -1;
    __syncthreads();
    if (t > sval[c]) sval[c] = t;
    __syncthreads();
  }
  labels[p] = fg ? sval[c] : SS;
  if (rs) areas[p] = 0;

  for (int off = 128; off > 0; off >>= 1) {
    if (c < off) sd[c] += sd[c + off];
    __syncthreads();
  }
  if (c == 0) atomicAdd(&mt->dsum[gm], sd[0]);
}

// Find with plain-store path compression (ECL-CC style). Safe concurrent with
// atomicMin linking: every stored value is an ancestor read from the live
// structure; parent strictly < child, so no cycles; roots only change via
// atomicMin, so the min-index-root invariant is preserved.
__device__ __forceinline__ int find_c(int* L, int x) {
  int p = L[x];
  if (p == x) return x;
  int root = p, q = L[root];
  while (q != root) { root = q; q = L[root]; }
  if (root != p) L[x] = root;
  return root;
}

// Komura-style union: always link larger root -> smaller root, so the final
// root is the component's minimum pixel index (matches reference labels).
__device__ void unite(int* L, int a, int b) {
  bool done = false;
  do {
    a = find_c(L, a);
    b = find_c(L, b);
    if (a < b)      { int old = atomicMin(&L[b], a); done = (old == b); b = old; }
    else if (b < a) { int old = atomicMin(&L[a], b); done = (old == a); a = old; }
    else done = true;
  } while (!done);
}

// Vertical unions with leftmost-contact dedup: for each (run, north-run)
// contact, exactly the leftmost contact pixel issues the unite.
//  - N-run / NW-run (their interval reaches col <= c): skip if W is fg
//    (W's north window [c-2,c] already touches that run).
//  - NE-run with N bg (interval starts at c+1): never covered by W; always do.
// fg test via labels (L[q]==SS iff bg: fg entries only ever hold fg indices).
__global__ void k_merge(int* __restrict__ labels) {
  int p    = blockIdx.x * blockDim.x + threadIdx.x;
  int lm   = p >> 16;
  int lidx = p & 0xFFFF;
  int* L   = labels + ((size_t)lm << 16);
  int v = L[lidx];
  if (v == SS) return;
  int r = lidx >> 8, c = lidx & 0xFF;
  if (r == 0) return;
  bool wfg = (c > 0) && (L[lidx - 1] != SS);
  int n = L[lidx - WW];
  if (!wfg) {
    if (n != SS) {
      unite(L, v, n);
    } else if (c > 0) {
      int nw = L[lidx - WW - 1];
      if (nw != SS) unite(L, v, nw);
    }
  }
  if (n == SS && c < WW - 1) {
    int ne = L[lidx - WW + 1];
    if (ne != SS) unite(L, v, ne);
  }
}

// Path-halving find (post-merge tree is static; races only lose compression).
__device__ __forceinline__ int find_halve(int* L, int x) {
  int p = L[x];
  while (p != x) {
    int gp = L[p];
    if (gp == p) return p;
    L[x] = gp;
    x = p; p = gp;
  }
  return x;
}

__global__ void k_flatten(int* __restrict__ labels, int* __restrict__ areas) {
  int p    = blockIdx.x * blockDim.x + threadIdx.x;
  int lm   = p >> 16;
  int lidx = p & 0xFFFF;
  int* L   = labels + ((size_t)lm << 16);
  int v = L[lidx];
  bool isfg = (v != SS);
  int rt = SS;
  if (isfg) {
    rt = find_halve(L, v);
    L[lidx] = rt;
  }
  // Wave-aggregated per-root area counting: one atomic per distinct root per
  // wave (consecutive lanes are consecutive pixels -> usually 1-3 roots).
  int lane = threadIdx.x & 63;
  bool pending = isfg;
  while (__any(pending)) {
    unsigned long long mask = __ballot(pending);
    int src  = __ffsll(mask) - 1;
    int lead = __shfl(rt, src);
    bool mine = pending && (rt == lead);
    unsigned long long grp = __ballot(mine);
    if (lane == src)
      atomicAdd(&areas[(lm << 16) + lead], (int)__popcll(grp));
    pending = pending && !mine;
  }
}

// key = (area << 17) | (SS - label): max key == (area desc, label asc) — the
// exact lax.top_k ordering. Only roots (labels[i]==i) carry nonzero area; the
// best zero-area label (min non-root index) is merged in explicitly so
// degenerate cases match lax.top_k exactly. Background area = SS - sum(areas).
__global__ void k_top2(const int* __restrict__ labels,
                       const int* __restrict__ areas, Meta* __restrict__ mt,
                       int c0) {
  int lm = blockIdx.x;
  int gm = c0 + lm;
  const int* Lm = labels + ((size_t)lm << 16);
  const int* A  = areas  + ((size_t)lm << 16);
  unsigned long long t1 = 0, t2 = 0;
  int mysum = 0;
  int locmin = SS;   // min index with labels[i] != i  (a zero-area label)
  for (int i = threadIdx.x; i < SS; i += blockDim.x) {
    int lab = Lm[i];
    if (lab == i) {
      int a = A[i];
      mysum += a;
      unsigned long long key =
          ((unsigned long long)a << 17) | (unsigned)(SS - i);
      if (key > t1) { t2 = t1; t1 = key; }
      else if (key > t2) { t2 = key; }
    } else if (i < locmin) {
      locmin = i;
    }
  }
  __shared__ unsigned long long s1[1024], s2[1024];
  __shared__ int ssum[1024], smin[1024];
  s1[threadIdx.x] = t1; s2[threadIdx.x] = t2;
  ssum[threadIdx.x] = mysum; smin[threadIdx.x] = locmin;
  __syncthreads();
  for (int off = blockDim.x >> 1; off > 0; off >>= 1) {
    if (threadIdx.x < off) {
      unsigned long long a1 = s1[threadIdx.x], a2 = s2[threadIdx.x];
      unsigned long long b1 = s1[threadIdx.x + off], b2 = s2[threadIdx.x + off];
      if (b1 > a1) { a2 = (a1 > b2) ? a1 : b2; a1 = b1; }
      else         { a2 = (a2 > b1) ? a2 : b1; }
      s1[threadIdx.x] = a1; s2[threadIdx.x] = a2;
      ssum[threadIdx.x] += ssum[threadIdx.x + off];
      smin[threadIdx.x] = min(smin[threadIdx.x], smin[threadIdx.x + off]);
    }
    __syncthreads();
  }
  if (threadIdx.x == 0) {
    unsigned long long a1 = s1[0], a2 = s2[0];
    // background candidate: label SS, area = SS - fgcnt, low bits 0
    unsigned long long bk = ((unsigned long long)(SS - ssum[0]) << 17);
    if (bk > a1) { a2 = a1; a1 = bk; }
    else if (bk > a2) { a2 = bk; }
    // best zero-area candidate: area 0, label = smin[0]
    unsigned long long kz = (unsigned long long)(unsigned)(SS - smin[0]);
    if (kz > a1) { a2 = a1; a1 = kz; }
    else if (kz > a2) { a2 = kz; }
    mt->second[gm] = SS - (int)(a2 & 0x1FFFF);
  }
}

// One block = one row: per-row col min/max reduce, then 4 atomics per row.
__global__ void k_bbox(const int* __restrict__ labels, Meta* __restrict__ mt,
                       int c0) {
  int p    = blockIdx.x * blockDim.x + threadIdx.x;
  int lm   = p >> 16;
  int lidx = p & 0xFFFF;
  int gm   = c0 + lm;
  int sec  = mt->second[gm];
  int lab  = labels[p];
  int r = lidx >> 8, c = lidx & 0xFF;
  bool sel = (lab == sec);
  __shared__ int smn[256], smx[256];
  smn[threadIdx.x] = sel ? c : WW;
  smx[threadIdx.x] = sel ? c : -1;
  __syncthreads();
  for (int off = 128; off > 0; off >>= 1) {
    if (threadIdx.x < off) {
      smn[threadIdx.x] = min(smn[threadIdx.x], smn[threadIdx.x + off]);
      smx[threadIdx.x] = max(smx[threadIdx.x], smx[threadIdx.x + off]);
    }
    __syncthreads();
  }
  if (threadIdx.x == 0 && smx[0] >= 0) {
    atomicMin(&mt->w0[gm], smn[0]);
    atomicMax(&mt->w1[gm], smx[0]);
    atomicMin(&mt->h0[gm], r);
    atomicMax(&mt->h1[gm], r);
  }
}

// One block per mask: sum m over the (inclusive) bbox, finish per-mask loss.
__global__ void k_inside(const float* __restrict__ in, Meta* __restrict__ mt,
                         int c0) {
  int lm = blockIdx.x;
  int gm = c0 + lm;
  int h0 = mt->h0[gm], h1 = mt->h1[gm], w0 = mt->w0[gm], w1 = mt->w1[gm];
  double acc = 0.0;
  if (h1 >= h0) {
    int bw  = w1 - w0 + 1;
    int tot = bw * (h1 - h0 + 1);
    const float* base = in + (size_t)gm * SS;
    for (int i = threadIdx.x; i < tot; i += blockDim.x) {
      int rr = h0 + i / bw, cc = w0 + i % bw;
      float x = base[rr * WW + cc];
      acc += (double)fmaxf((x + 1.0f) * 0.5f, 0.0f);
    }
  }
  __shared__ double sd[512];
  sd[threadIdx.x] = acc;
  __syncthreads();
  for (int off = (int)blockDim.x >> 1; off > 0; off >>= 1) {
    if (threadIdx.x < off) sd[threadIdx.x] += sd[threadIdx.x + off];
    __syncthreads();
  }
  if (threadIdx.x == 0)
    mt->dloss[gm] = (mt->dsum[gm] - sd[0]) / (double)SS;
}

__global__ void k_final(const Meta* __restrict__ mt, float* __restrict__ out) {
  __shared__ double sd[NM];
  int t = threadIdx.x;
  sd[t] = mt->dloss[t];
  __syncthreads();
  for (int off = 64; off > 0; off >>= 1) {
    if (t < off) sd[t] += sd[t + off];
    __syncthreads();
  }
  if (t == 0) out[0] = (float)(sd[0] / (double)NM);
}

extern "C" void kernel_launch(void* const* d_in, const int* in_sizes, int n_in,
                              void* d_out, int out_size, void* d_ws,
                              size_t ws_size, hipStream_t stream) {
  const float* in = (const float*)d_in[0];
  float* out = (float*)d_out;

  Meta* mt = (Meta*)d_ws;
  const size_t meta_bytes = (sizeof(Meta) + 255) & ~(size_t)255;
  char* base = (char*)d_ws + meta_bytes;
  size_t avail = (ws_size > meta_bytes) ? (ws_size - meta_bytes) : 0;
  int chunk = (int)(avail / (2ull * SS * sizeof(int)));  // labels + areas
  if (chunk > NM) chunk = NM;
  if (chunk < 1) return;  // insufficient workspace (would fail validation)

  int* labels = (int*)base;
  int* areas  = labels + (size_t)chunk * SS;

  k_meta_init<<<1, 128, 0, stream>>>(mt);
  for (int c0 = 0; c0 < NM; c0 += chunk) {
    int cn = (chunk < NM - c0) ? chunk : (NM - c0);
    int blocks = cn * (SS / 256);
    k_init   <<<blocks, 256, 0, stream>>>(in, c0, labels, areas, mt);
    k_merge  <<<blocks, 256, 0, stream>>>(labels);
    k_flatten<<<blocks, 256, 0, stream>>>(labels, areas);
    k_top2   <<<cn,    1024, 0, stream>>>(labels, areas, mt, c0);
    k_bbox   <<<blocks, 256, 0, stream>>>(labels, mt, c0);
    k_inside <<<cn,     512, 0, stream>>>(in, mt, c0);
  }
  k_final<<<1, 128, 0, stream>>>(mt, out);
}

// Round 4
// 543.293 us; speedup vs baseline: 5.6445x; 1.6386x over previous
//
#include <hip/hip_runtime.h>

#define HH 256
#define WW 256
#define SS 65536   // pixels per mask; also the background sentinel label
#define NM 128     // B*K masks
#define TR 32      // rows per tile (k_local)
#define NT 8       // tiles per mask
#define TPX (TR * WW)  // 8192 pixels per tile

struct Meta {
  double dsum[NM];    // total sum of m per mask
  double dloss[NM];   // per-mask loss
  int second[NM];     // second-largest-area label (0..SS)
  int h0[NM]; int h1[NM]; int w0[NM]; int w1[NM];  // bbox (inclusive h1,w1)
};

__global__ void k_meta_init(Meta* mt) {
  int i = threadIdx.x;
  if (i < NM) {
    mt->dsum[i] = 0.0; mt->dloss[i] = 0.0; mt->second[i] = -1;
    mt->h0[i] = HH; mt->h1[i] = -1; mt->w0[i] = WW; mt->w1[i] = -1;
  }
}

// Find with plain-store path compression (ECL-CC style). Safe concurrent with
// atomicMin linking (LDS or global): stored values are live ancestors; parent
// strictly < child -> acyclic; roots only change via atomicMin.
__device__ __forceinline__ int find_c(int* L, int x) {
  int p = L[x];
  if (p == x) return x;
  int root = p, q = L[root];
  while (q != root) { root = q; q = L[root]; }
  if (root != p) L[x] = root;
  return root;
}

// Komura-style union: link larger root -> smaller root, so the final root is
// the component's minimum pixel index (matches reference labels).
__device__ void unite(int* L, int a, int b) {
  bool done = false;
  do {
    a = find_c(L, a);
    b = find_c(L, b);
    if (a < b)      { int old = atomicMin(&L[b], a); done = (old == b); b = old; }
    else if (b < a) { int old = atomicMin(&L[a], b); done = (old == a); a = old; }
    else done = true;
  } while (!done);
}

// Path-halving find (static tree; racing stores only lose compression).
__device__ __forceinline__ int find_halve(int* L, int x) {
  int p = L[x];
  while (p != x) {
    int gp = L[p];
    if (gp == p) return p;
    L[x] = gp;
    x = p; p = gp;
  }
  return x;
}

// One block = one 32x256 tile. Fused: input read + m/dsum + fg row bitmasks +
// run-start labeling (clz on bitmask, no scan) + intra-tile union-find in LDS
// + local flatten + resolved global label write + sparse area zeroing.
// Intra-row pairs are free (run labeling); vertical unions use LDS atomics.
__global__ __launch_bounds__(512)
void k_local(const float* __restrict__ in, int cb,
             int* __restrict__ labels, int* __restrict__ areas,
             Meta* __restrict__ mt) {
  __shared__ int slab[TPX];                       // 32 KB
  __shared__ unsigned long long sfgw[TR][4];      // 1 KB: fg row bitmasks
  __shared__ unsigned short sfg16[TR][16];        // 1 KB: 16-bit chunks
  __shared__ double sred[8];

  int q    = blockIdx.x;
  int lm   = q >> 3;          // chunk-local mask
  int tile = q & 7;
  int R0   = tile << 5;       // first mask-row of tile
  int tid  = threadIdx.x;
  int r    = tid >> 4;        // tile-local row 0..31
  int cs   = tid & 15;        // 16-col chunk slot
  int c0   = cs << 4;
  int gm   = cb + lm;
  int grow = R0 + r;

  const float4* src =
      (const float4*)(in + ((size_t)gm << 16) + (grow << 8) + c0);
  double dsum = 0.0;
  unsigned int fgbits = 0;
  for (int k = 0; k < 4; k++) {
    float4 v = src[k];
    float m0 = fmaxf((v.x + 1.0f) * 0.5f, 0.0f);
    float m1 = fmaxf((v.y + 1.0f) * 0.5f, 0.0f);
    float m2 = fmaxf((v.z + 1.0f) * 0.5f, 0.0f);
    float m3 = fmaxf((v.w + 1.0f) * 0.5f, 0.0f);
    dsum += (double)m0 + (double)m1 + (double)m2 + (double)m3;
    fgbits |= ((m0 > 0.5f) ? 1u : 0u) << (4 * k);
    fgbits |= ((m1 > 0.5f) ? 1u : 0u) << (4 * k + 1);
    fgbits |= ((m2 > 0.5f) ? 1u : 0u) << (4 * k + 2);
    fgbits |= ((m3 > 0.5f) ? 1u : 0u) << (4 * k + 3);
  }
  sfg16[r][cs] = (unsigned short)fgbits;
  __syncthreads();
  if (cs < 4) {
    int b = cs * 4;
    sfgw[r][cs] = (unsigned long long)sfg16[r][b]
                | ((unsigned long long)sfg16[r][b + 1] << 16)
                | ((unsigned long long)sfg16[r][b + 2] << 32)
                | ((unsigned long long)sfg16[r][b + 3] << 48);
  }
  __syncthreads();

  unsigned long long myw[4], nww[4];
  for (int i = 0; i < 4; i++) {
    myw[i] = sfgw[r][i];
    nww[i] = (r > 0) ? sfgw[r - 1][i] : 0ull;
  }

  // Init: label = run-start node (root of its run); bg = sentinel.
  // Zero `areas` only at run starts (the only atomicAdd/read targets).
  for (int j = 0; j < 16; j++) {
    int c = c0 + j;
    int node = (r << 8) + c;
    int lab = 0x7FFFFFFF;
    if ((fgbits >> j) & 1) {
      int b = c & 63, w = c >> 6;
      unsigned long long z = ~myw[w] & (b ? ((1ull << b) - 1) : 0ull);
      int w2 = w;
      while (z == 0 && w2 > 0) { w2--; z = ~myw[w2]; }
      int start = z ? ((w2 << 6) + (63 - (int)__clzll(z)) + 1) : 0;
      lab = (r << 8) + start;
      if (start == c)
        areas[((size_t)lm << 16) + (grow << 8) + c] = 0;
    }
    slab[node] = lab;
  }
  __syncthreads();

  // Vertical unions (leftmost-contact dedup), all in LDS.
  if (r > 0) {
    for (int j = 0; j < 16; j++) {
      if (!((fgbits >> j) & 1)) continue;
      int c  = c0 + j;
      int me = (r << 8) + c;
      bool wfg = (c > 0) && ((myw[(c - 1) >> 6] >> ((c - 1) & 63)) & 1);
      bool nfg = (nww[c >> 6] >> (c & 63)) & 1;
      if (!wfg) {
        if (nfg) unite(slab, me, me - WW);
        else if (c > 0 && ((nww[(c - 1) >> 6] >> ((c - 1) & 63)) & 1))
          unite(slab, me, me - WW - 1);
      }
      if (!nfg && c < WW - 1 && ((nww[(c + 1) >> 6] >> ((c + 1) & 63)) & 1))
        unite(slab, me, me - WW + 1);
    }
  }
  __syncthreads();

  // Local flatten + resolved global write (tile node -> mask pixel index).
  int* Lg = labels + ((size_t)lm << 16);
  int outv[16];
  for (int j = 0; j < 16; j++) {
    int v = SS;
    if ((fgbits >> j) & 1)
      v = (R0 << 8) + find_halve(slab, (r << 8) + (c0 + j));
    outv[j] = v;
  }
  int4* dst = (int4*)(Lg + (grow << 8) + c0);
  dst[0] = make_int4(outv[0],  outv[1],  outv[2],  outv[3]);
  dst[1] = make_int4(outv[4],  outv[5],  outv[6],  outv[7]);
  dst[2] = make_int4(outv[8],  outv[9],  outv[10], outv[11]);
  dst[3] = make_int4(outv[12], outv[13], outv[14], outv[15]);

  for (int off = 32; off > 0; off >>= 1) dsum += __shfl_down(dsum, off);
  if ((tid & 63) == 0) sred[tid >> 6] = dsum;
  __syncthreads();
  if (tid == 0) {
    double t = 0.0;
    for (int i = 0; i < 8; i++) t += sred[i];
    atomicAdd(&mt->dsum[gm], t);
  }
}

// Global seam merge: only the 7 tile-boundary rows per mask (dedup as before).
__global__ void k_seam(int* __restrict__ labels) {
  int sidx = blockIdx.x;
  int lm = sidx / 7, s = sidx % 7;
  int R = (s + 1) * TR;
  int c = threadIdx.x;
  int lidx = (R << 8) + c;
  int* L = labels + ((size_t)lm << 16);
  int v = L[lidx];
  if (v == SS) return;
  bool wfg = (c > 0) && (L[lidx - 1] != SS);
  int n = L[lidx - WW];
  if (!wfg) {
    if (n != SS) unite(L, v, n);
    else if (c > 0) {
      int nw = L[lidx - WW - 1];
      if (nw != SS) unite(L, v, nw);
    }
  }
  if (n == SS && c < WW - 1) {
    int ne = L[lidx - WW + 1];
    if (ne != SS) unite(L, v, ne);
  }
}

__global__ void k_flatten(int* __restrict__ labels, int* __restrict__ areas) {
  int p    = blockIdx.x * blockDim.x + threadIdx.x;
  int lm   = p >> 16;
  int lidx = p & 0xFFFF;
  int* L   = labels + ((size_t)lm << 16);
  int v = L[lidx];
  bool isfg = (v != SS);
  int rt = SS;
  if (isfg) {
    rt = find_halve(L, v);
    L[lidx] = rt;
  }
  // Wave-aggregated per-root area counting.
  int lane = threadIdx.x & 63;
  bool pending = isfg;
  while (__any(pending)) {
    unsigned long long mask = __ballot(pending);
    int src  = __ffsll(mask) - 1;
    int lead = __shfl(rt, src);
    bool mine = pending && (rt == lead);
    unsigned long long grp = __ballot(mine);
    if (lane == src)
      atomicAdd(&areas[(lm << 16) + lead], (int)__popcll(grp));
    pending = pending && !mine;
  }
}

// key = (area << 17) | (SS - label): max key == (area desc, label asc) — the
// exact lax.top_k ordering. Only final roots (labels[i]==i) carry area; best
// zero-area label = min non-root index; background area = SS - sum(areas).
__global__ void k_top2(const int* __restrict__ labels,
                       const int* __restrict__ areas, Meta* __restrict__ mt,
                       int c0) {
  int lm = blockIdx.x;
  int gm = c0 + lm;
  const int* Lm = labels + ((size_t)lm << 16);
  const int* A  = areas  + ((size_t)lm << 16);
  unsigned long long t1 = 0, t2 = 0;
  int mysum = 0;
  int locmin = SS;
  for (int i = threadIdx.x; i < SS; i += blockDim.x) {
    int lab = Lm[i];
    if (lab == i) {
      int a = A[i];
      mysum += a;
      unsigned long long key =
          ((unsigned long long)a << 17) | (unsigned)(SS - i);
      if (key > t1) { t2 = t1; t1 = key; }
      else if (key > t2) { t2 = key; }
    } else if (i < locmin) {
      locmin = i;
    }
  }
  __shared__ unsigned long long s1[1024], s2[1024];
  __shared__ int ssum[1024], smin[1024];
  s1[threadIdx.x] = t1; s2[threadIdx.x] = t2;
  ssum[threadIdx.x] = mysum; smin[threadIdx.x] = locmin;
  __syncthreads();
  for (int off = blockDim.x >> 1; off > 0; off >>= 1) {
    if (threadIdx.x < off) {
      unsigned long long a1 = s1[threadIdx.x], a2 = s2[threadIdx.x];
      unsigned long long b1 = s1[threadIdx.x + off], b2 = s2[threadIdx.x + off];
      if (b1 > a1) { a2 = (a1 > b2) ? a1 : b2; a1 = b1; }
      else         { a2 = (a2 > b1) ? a2 : b1; }
      s1[threadIdx.x] = a1; s2[threadIdx.x] = a2;
      ssum[threadIdx.x] += ssum[threadIdx.x + off];
      smin[threadIdx.x] = min(smin[threadIdx.x], smin[threadIdx.x + off]);
    }
    __syncthreads();
  }
  if (threadIdx.x == 0) {
    unsigned long long a1 = s1[0], a2 = s2[0];
    unsigned long long bk = ((unsigned long long)(SS - ssum[0]) << 17);
    if (bk > a1) { a2 = a1; a1 = bk; }
    else if (bk > a2) { a2 = bk; }
    unsigned long long kz = (unsigned long long)(unsigned)(SS - smin[0]);
    if (kz > a1) { a2 = a1; a1 = kz; }
    else if (kz > a2) { a2 = kz; }
    mt->second[gm] = SS - (int)(a2 & 0x1FFFF);
  }
}

// One block = one row: per-row col min/max reduce, then 4 atomics per row.
__global__ void k_bbox(const int* __restrict__ labels, Meta* __restrict__ mt,
                       int c0) {
  int p    = blockIdx.x * blockDim.x + threadIdx.x;
  int lm   = p >> 16;
  int lidx = p & 0xFFFF;
  int gm   = c0 + lm;
  int sec  = mt->second[gm];
  int lab  = labels[p];
  int r = lidx >> 8, c = lidx & 0xFF;
  bool sel = (lab == sec);
  __shared__ int smn[256], smx[256];
  smn[threadIdx.x] = sel ? c : WW;
  smx[threadIdx.x] = sel ? c : -1;
  __syncthreads();
  for (int off = 128; off > 0; off >>= 1) {
    if (threadIdx.x < off) {
      smn[threadIdx.x] = min(smn[threadIdx.x], smn[threadIdx.x + off]);
      smx[threadIdx.x] = max(smx[threadIdx.x], smx[threadIdx.x + off]);
    }
    __syncthreads();
  }
  if (threadIdx.x == 0 && smx[0] >= 0) {
    atomicMin(&mt->w0[gm], smn[0]);
    atomicMax(&mt->w1[gm], smx[0]);
    atomicMin(&mt->h0[gm], r);
    atomicMax(&mt->h1[gm], r);
  }
}

// One block per mask: sum m over the (inclusive) bbox, finish per-mask loss.
__global__ void k_inside(const float* __restrict__ in, Meta* __restrict__ mt,
                         int c0) {
  int lm = blockIdx.x;
  int gm = c0 + lm;
  int h0 = mt->h0[gm], h1 = mt->h1[gm], w0 = mt->w0[gm], w1 = mt->w1[gm];
  double acc = 0.0;
  if (h1 >= h0) {
    int bw  = w1 - w0 + 1;
    int tot = bw * (h1 - h0 + 1);
    const float* base = in + (size_t)gm * SS;
    for (int i = threadIdx.x; i < tot; i += blockDim.x) {
      int rr = h0 + i / bw, cc = w0 + i % bw;
      float x = base[rr * WW + cc];
      acc += (double)fmaxf((x + 1.0f) * 0.5f, 0.0f);
    }
  }
  __shared__ double sd[512];
  sd[threadIdx.x] = acc;
  __syncthreads();
  for (int off = (int)blockDim.x >> 1; off > 0; off >>= 1) {
    if (threadIdx.x < off) sd[threadIdx.x] += sd[threadIdx.x + off];
    __syncthreads();
  }
  if (threadIdx.x == 0)
    mt->dloss[gm] = (mt->dsum[gm] - sd[0]) / (double)SS;
}

__global__ void k_final(const Meta* __restrict__ mt, float* __restrict__ out) {
  __shared__ double sd[NM];
  int t = threadIdx.x;
  sd[t] = mt->dloss[t];
  __syncthreads();
  for (int off = 64; off > 0; off >>= 1) {
    if (t < off) sd[t] += sd[t + off];
    __syncthreads();
  }
  if (t == 0) out[0] = (float)(sd[0] / (double)NM);
}

extern "C" void kernel_launch(void* const* d_in, const int* in_sizes, int n_in,
                              void* d_out, int out_size, void* d_ws,
                              size_t ws_size, hipStream_t stream) {
  const float* in = (const float*)d_in[0];
  float* out = (float*)d_out;

  Meta* mt = (Meta*)d_ws;
  const size_t meta_bytes = (sizeof(Meta) + 255) & ~(size_t)255;
  char* base = (char*)d_ws + meta_bytes;
  size_t avail = (ws_size > meta_bytes) ? (ws_size - meta_bytes) : 0;
  int chunk = (int)(avail / (2ull * SS * sizeof(int)));  // labels + areas
  if (chunk > NM) chunk = NM;
  if (chunk < 1) return;  // insufficient workspace (would fail validation)

  int* labels = (int*)base;
  int* areas  = labels + (size_t)chunk * SS;

  k_meta_init<<<1, 128, 0, stream>>>(mt);
  for (int c0 = 0; c0 < NM; c0 += chunk) {
    int cn = (chunk < NM - c0) ? chunk : (NM - c0);
    int blocks = cn * (SS / 256);
    k_local  <<<cn * NT, 512, 0, stream>>>(in, c0, labels, areas, mt);
    k_seam   <<<cn * (NT - 1), 256, 0, stream>>>(labels);
    k_flatten<<<blocks, 256, 0, stream>>>(labels, areas);
    k_top2   <<<cn,    1024, 0, stream>>>(labels, areas, mt, c0);
    k_bbox   <<<blocks, 256, 0, stream>>>(labels, mt, c0);
    k_inside <<<cn,     512, 0, stream>>>(in, mt, c0);
  }
  k_final<<<1, 128, 0, stream>>>(mt, out);
}

// Round 5
// 301.609 us; speedup vs baseline: 10.1674x; 1.8013x over previous
//
#include <hip/hip_runtime.h>

#define HH 256
#define WW 256
#define SS 65536   // pixels per mask; also the background sentinel label
#define NM 128     // B*K masks
#define TR 32      // rows per tile (k_local)
#define NT 8       // tiles per mask
#define TPX (TR * WW)  // 8192 pixels per tile

struct Meta {
  double dsum[NM];    // total sum of m per mask
  double dins[NM];    // sum of m inside suppressed bbox per mask
  int second[NM];     // second-largest-area label (0..SS)
  int h0[NM]; int h1[NM]; int w0[NM]; int w1[NM];  // bbox (inclusive h1,w1)
};

__global__ void k_meta_init(Meta* mt) {
  int i = threadIdx.x;
  if (i < NM) {
    mt->dsum[i] = 0.0; mt->dins[i] = 0.0; mt->second[i] = -1;
    mt->h0[i] = HH; mt->h1[i] = -1; mt->w0[i] = WW; mt->w1[i] = -1;
  }
}

// Find with plain-store path compression (ECL-CC style). Safe concurrent with
// atomicMin linking (LDS or global): stored values are live ancestors; parent
// strictly < child -> acyclic; roots only change via atomicMin.
__device__ __forceinline__ int find_c(int* L, int x) {
  int p = L[x];
  if (p == x) return x;
  int root = p, q = L[root];
  while (q != root) { root = q; q = L[root]; }
  if (root != p) L[x] = root;
  return root;
}

// Komura-style union: link larger root -> smaller root, so the final root is
// the component's minimum pixel index (matches reference labels).
__device__ void unite(int* L, int a, int b) {
  bool done = false;
  do {
    a = find_c(L, a);
    b = find_c(L, b);
    if (a < b)      { int old = atomicMin(&L[b], a); done = (old == b); b = old; }
    else if (b < a) { int old = atomicMin(&L[a], b); done = (old == a); a = old; }
    else done = true;
  } while (!done);
}

// Path-halving find (static tree; racing stores only lose compression).
__device__ __forceinline__ int find_halve(int* L, int x) {
  int p = L[x];
  while (p != x) {
    int gp = L[p];
    if (gp == p) return p;
    L[x] = gp;
    x = p; p = gp;
  }
  return x;
}

// One block = one 32x256 tile. Fused: input read + m/dsum + fg row bitmasks +
// run-start labeling (clz on bitmask, no scan) + intra-tile union-find in LDS
// + local flatten + resolved global label write + sparse area zeroing.
__global__ __launch_bounds__(512)
void k_local(const float* __restrict__ in, int cb,
             int* __restrict__ labels, int* __restrict__ areas,
             Meta* __restrict__ mt) {
  __shared__ int slab[TPX];                       // 32 KB
  __shared__ unsigned long long sfgw[TR][4];      // 1 KB: fg row bitmasks
  __shared__ unsigned short sfg16[TR][16];        // 1 KB: 16-bit chunks
  __shared__ double sred[8];

  int q    = blockIdx.x;
  int lm   = q >> 3;          // chunk-local mask
  int tile = q & 7;
  int R0   = tile << 5;       // first mask-row of tile
  int tid  = threadIdx.x;
  int r    = tid >> 4;        // tile-local row 0..31
  int cs   = tid & 15;        // 16-col chunk slot
  int c0   = cs << 4;
  int gm   = cb + lm;
  int grow = R0 + r;

  const float4* src =
      (const float4*)(in + ((size_t)gm << 16) + (grow << 8) + c0);
  double dsum = 0.0;
  unsigned int fgbits = 0;
  for (int k = 0; k < 4; k++) {
    float4 v = src[k];
    float m0 = fmaxf((v.x + 1.0f) * 0.5f, 0.0f);
    float m1 = fmaxf((v.y + 1.0f) * 0.5f, 0.0f);
    float m2 = fmaxf((v.z + 1.0f) * 0.5f, 0.0f);
    float m3 = fmaxf((v.w + 1.0f) * 0.5f, 0.0f);
    dsum += (double)m0 + (double)m1 + (double)m2 + (double)m3;
    fgbits |= ((m0 > 0.5f) ? 1u : 0u) << (4 * k);
    fgbits |= ((m1 > 0.5f) ? 1u : 0u) << (4 * k + 1);
    fgbits |= ((m2 > 0.5f) ? 1u : 0u) << (4 * k + 2);
    fgbits |= ((m3 > 0.5f) ? 1u : 0u) << (4 * k + 3);
  }
  sfg16[r][cs] = (unsigned short)fgbits;
  __syncthreads();
  if (cs < 4) {
    int b = cs * 4;
    sfgw[r][cs] = (unsigned long long)sfg16[r][b]
                | ((unsigned long long)sfg16[r][b + 1] << 16)
                | ((unsigned long long)sfg16[r][b + 2] << 32)
                | ((unsigned long long)sfg16[r][b + 3] << 48);
  }
  __syncthreads();

  unsigned long long myw[4], nww[4];
  for (int i = 0; i < 4; i++) {
    myw[i] = sfgw[r][i];
    nww[i] = (r > 0) ? sfgw[r - 1][i] : 0ull;
  }

  // Init: label = run-start node; bg = sentinel. Zero `areas` only at run
  // starts (the only atomicAdd/read targets).
  for (int j = 0; j < 16; j++) {
    int c = c0 + j;
    int node = (r << 8) + c;
    int lab = 0x7FFFFFFF;
    if ((fgbits >> j) & 1) {
      int b = c & 63, w = c >> 6;
      unsigned long long z = ~myw[w] & (b ? ((1ull << b) - 1) : 0ull);
      int w2 = w;
      while (z == 0 && w2 > 0) { w2--; z = ~myw[w2]; }
      int start = z ? ((w2 << 6) + (63 - (int)__clzll(z)) + 1) : 0;
      lab = (r << 8) + start;
      if (start == c)
        areas[((size_t)lm << 16) + (grow << 8) + c] = 0;
    }
    slab[node] = lab;
  }
  __syncthreads();

  // Vertical unions (leftmost-contact dedup), all in LDS.
  if (r > 0) {
    for (int j = 0; j < 16; j++) {
      if (!((fgbits >> j) & 1)) continue;
      int c  = c0 + j;
      int me = (r << 8) + c;
      bool wfg = (c > 0) && ((myw[(c - 1) >> 6] >> ((c - 1) & 63)) & 1);
      bool nfg = (nww[c >> 6] >> (c & 63)) & 1;
      if (!wfg) {
        if (nfg) unite(slab, me, me - WW);
        else if (c > 0 && ((nww[(c - 1) >> 6] >> ((c - 1) & 63)) & 1))
          unite(slab, me, me - WW - 1);
      }
      if (!nfg && c < WW - 1 && ((nww[(c + 1) >> 6] >> ((c + 1) & 63)) & 1))
        unite(slab, me, me - WW + 1);
    }
  }
  __syncthreads();

  // Local flatten + resolved global write (tile node -> mask pixel index).
  int* Lg = labels + ((size_t)lm << 16);
  int outv[16];
  for (int j = 0; j < 16; j++) {
    int v = SS;
    if ((fgbits >> j) & 1)
      v = (R0 << 8) + find_halve(slab, (r << 8) + (c0 + j));
    outv[j] = v;
  }
  int4* dst = (int4*)(Lg + (grow << 8) + c0);
  dst[0] = make_int4(outv[0],  outv[1],  outv[2],  outv[3]);
  dst[1] = make_int4(outv[4],  outv[5],  outv[6],  outv[7]);
  dst[2] = make_int4(outv[8],  outv[9],  outv[10], outv[11]);
  dst[3] = make_int4(outv[12], outv[13], outv[14], outv[15]);

  for (int off = 32; off > 0; off >>= 1) dsum += __shfl_down(dsum, off);
  if ((tid & 63) == 0) sred[tid >> 6] = dsum;
  __syncthreads();
  if (tid == 0) {
    double t = 0.0;
    for (int i = 0; i < 8; i++) t += sred[i];
    atomicAdd(&mt->dsum[gm], t);
  }
}

// Global seam merge: only the 7 tile-boundary rows per mask (dedup as before).
__global__ void k_seam(int* __restrict__ labels) {
  int sidx = blockIdx.x;
  int lm = sidx / 7, s = sidx % 7;
  int R = (s + 1) * TR;
  int c = threadIdx.x;
  int lidx = (R << 8) + c;
  int* L = labels + ((size_t)lm << 16);
  int v = L[lidx];
  if (v == SS) return;
  bool wfg = (c > 0) && (L[lidx - 1] != SS);
  int n = L[lidx - WW];
  if (!wfg) {
    if (n != SS) unite(L, v, n);
    else if (c > 0) {
      int nw = L[lidx - WW - 1];
      if (nw != SS) unite(L, v, nw);
    }
  }
  if (n == SS && c < WW - 1) {
    int ne = L[lidx - WW + 1];
    if (ne != SS) unite(L, v, ne);
  }
}

__global__ void k_flatten(int* __restrict__ labels, int* __restrict__ areas) {
  int p    = blockIdx.x * blockDim.x + threadIdx.x;
  int lm   = p >> 16;
  int lidx = p & 0xFFFF;
  int* L   = labels + ((size_t)lm << 16);
  int v = L[lidx];
  bool isfg = (v != SS);
  int rt = SS;
  if (isfg) {
    rt = find_halve(L, v);
    L[lidx] = rt;
  }
  // Wave-aggregated per-root area counting.
  int lane = threadIdx.x & 63;
  bool pending = isfg;
  while (__any(pending)) {
    unsigned long long mask = __ballot(pending);
    int src  = __ffsll(mask) - 1;
    int lead = __shfl(rt, src);
    bool mine = pending && (rt == lead);
    unsigned long long grp = __ballot(mine);
    if (lane == src)
      atomicAdd(&areas[(lm << 16) + lead], (int)__popcll(grp));
    pending = pending && !mine;
  }
}

// key = (area << 17) | (SS - label): max key == (area desc, label asc) — the
// exact lax.top_k ordering. Only final roots (labels[i]==i) carry area; best
// zero-area label = min non-root index; background area = SS - sum(areas).
__global__ void k_top2(const int* __restrict__ labels,
                       const int* __restrict__ areas, Meta* __restrict__ mt,
                       int c0) {
  int lm = blockIdx.x;
  int gm = c0 + lm;
  const int* Lm = labels + ((size_t)lm << 16);
  const int* A  = areas  + ((size_t)lm << 16);
  unsigned long long t1 = 0, t2 = 0;
  int mysum = 0;
  int locmin = SS;
  for (int i = threadIdx.x; i < SS; i += blockDim.x) {
    int lab = Lm[i];
    if (lab == i) {
      int a = A[i];
      mysum += a;
      unsigned long long key =
          ((unsigned long long)a << 17) | (unsigned)(SS - i);
      if (key > t1) { t2 = t1; t1 = key; }
      else if (key > t2) { t2 = key; }
    } else if (i < locmin) {
      locmin = i;
    }
  }
  __shared__ unsigned long long s1[1024], s2[1024];
  __shared__ int ssum[1024], smin[1024];
  s1[threadIdx.x] = t1; s2[threadIdx.x] = t2;
  ssum[threadIdx.x] = mysum; smin[threadIdx.x] = locmin;
  __syncthreads();
  for (int off = blockDim.x >> 1; off > 0; off >>= 1) {
    if (threadIdx.x < off) {
      unsigned long long a1 = s1[threadIdx.x], a2 = s2[threadIdx.x];
      unsigned long long b1 = s1[threadIdx.x + off], b2 = s2[threadIdx.x + off];
      if (b1 > a1) { a2 = (a1 > b2) ? a1 : b2; a1 = b1; }
      else         { a2 = (a2 > b1) ? a2 : b1; }
      s1[threadIdx.x] = a1; s2[threadIdx.x] = a2;
      ssum[threadIdx.x] += ssum[threadIdx.x + off];
      smin[threadIdx.x] = min(smin[threadIdx.x], smin[threadIdx.x + off]);
    }
    __syncthreads();
  }
  if (threadIdx.x == 0) {
    unsigned long long a1 = s1[0], a2 = s2[0];
    unsigned long long bk = ((unsigned long long)(SS - ssum[0]) << 17);
    if (bk > a1) { a2 = a1; a1 = bk; }
    else if (bk > a2) { a2 = bk; }
    unsigned long long kz = (unsigned long long)(unsigned)(SS - smin[0]);
    if (kz > a1) { a2 = a1; a1 = kz; }
    else if (kz > a2) { a2 = kz; }
    mt->second[gm] = SS - (int)(a2 & 0x1FFFF);
  }
}

// 16 blocks per mask, 1024 threads, int4 loads, wave-shuffle reductions only
// (no LDS tree, 1 barrier), 4 atomics per block (16x fewer than before).
__global__ __launch_bounds__(1024)
void k_bbox(const int* __restrict__ labels, Meta* __restrict__ mt, int c0) {
  int b   = blockIdx.x;
  int lm  = b >> 4;
  int seg = b & 15;           // 16-row segment
  int gm  = c0 + lm;
  int sec = mt->second[gm];
  const int4* L4 =
      (const int4*)(labels + ((size_t)lm << 16) + (seg << 12));
  int tid  = threadIdx.x;
  int4 v   = L4[tid];
  int base = tid << 2;
  int r = (seg << 4) + (base >> 8);
  int c = base & 0xFF;
  int cmn = WW, cmx = -1;
  if (v.x == sec) { cmn = c;               cmx = c; }
  if (v.y == sec) { cmn = min(cmn, c + 1); cmx = max(cmx, c + 1); }
  if (v.z == sec) { cmn = min(cmn, c + 2); cmx = max(cmx, c + 2); }
  if (v.w == sec) { cmn = min(cmn, c + 3); cmx = max(cmx, c + 3); }
  int rmn = (cmx >= 0) ? r : HH;
  int rmx = (cmx >= 0) ? r : -1;
  for (int off = 32; off > 0; off >>= 1) {
    cmn = min(cmn, __shfl_down(cmn, off));
    cmx = max(cmx, __shfl_down(cmx, off));
    rmn = min(rmn, __shfl_down(rmn, off));
    rmx = max(rmx, __shfl_down(rmx, off));
  }
  __shared__ int s0[16], s1[16], s2[16], s3[16];
  int wid = tid >> 6, lane = tid & 63;
  if (lane == 0) { s0[wid] = cmn; s1[wid] = cmx; s2[wid] = rmn; s3[wid] = rmx; }
  __syncthreads();
  if (tid < 16) {
    cmn = s0[tid]; cmx = s1[tid]; rmn = s2[tid]; rmx = s3[tid];
    for (int off = 8; off > 0; off >>= 1) {
      cmn = min(cmn, __shfl_down(cmn, off));
      cmx = max(cmx, __shfl_down(cmx, off));
      rmn = min(rmn, __shfl_down(rmn, off));
      rmx = max(rmx, __shfl_down(rmx, off));
    }
    if (tid == 0 && cmx >= 0) {
      atomicMin(&mt->w0[gm], cmn);
      atomicMax(&mt->w1[gm], cmx);
      atomicMin(&mt->h0[gm], rmn);
      atomicMax(&mt->h1[gm], rmx);
    }
  }
}

// 8 blocks per mask (rows h0+seg, step 8), 256 threads cover the col range
// (bw <= 256); double atomicAdd partials into dins.
__global__ void k_inside(const float* __restrict__ in, Meta* __restrict__ mt,
                         int c0) {
  int b = blockIdx.x;
  int lm = b >> 3, seg = b & 7;
  int gm = c0 + lm;
  int h0 = mt->h0[gm], h1 = mt->h1[gm], w0 = mt->w0[gm], w1 = mt->w1[gm];
  double acc = 0.0;
  if (h1 >= h0) {
    int cc = w0 + threadIdx.x;
    if (cc <= w1) {
      const float* base = in + ((size_t)gm << 16);
      for (int rr = h0 + seg; rr <= h1; rr += 8) {
        float x = base[(rr << 8) + cc];
        acc += (double)fmaxf((x + 1.0f) * 0.5f, 0.0f);
      }
    }
  }
  for (int off = 32; off > 0; off >>= 1) acc += __shfl_down(acc, off);
  __shared__ double sd[4];
  int wid = threadIdx.x >> 6, lane = threadIdx.x & 63;
  if (lane == 0) sd[wid] = acc;
  __syncthreads();
  if (threadIdx.x == 0) {
    double t = sd[0] + sd[1] + sd[2] + sd[3];
    if (t != 0.0) atomicAdd(&mt->dins[gm], t);
  }
}

__global__ void k_final(const Meta* __restrict__ mt, float* __restrict__ out) {
  __shared__ double sd[NM];
  int t = threadIdx.x;
  sd[t] = (mt->dsum[t] - mt->dins[t]) / (double)SS;
  __syncthreads();
  for (int off = 64; off > 0; off >>= 1) {
    if (t < off) sd[t] += sd[t + off];
    __syncthreads();
  }
  if (t == 0) out[0] = (float)(sd[0] / (double)NM);
}

extern "C" void kernel_launch(void* const* d_in, const int* in_sizes, int n_in,
                              void* d_out, int out_size, void* d_ws,
                              size_t ws_size, hipStream_t stream) {
  const float* in = (const float*)d_in[0];
  float* out = (float*)d_out;

  Meta* mt = (Meta*)d_ws;
  const size_t meta_bytes = (sizeof(Meta) + 255) & ~(size_t)255;
  char* base = (char*)d_ws + meta_bytes;
  size_t avail = (ws_size > meta_bytes) ? (ws_size - meta_bytes) : 0;
  int chunk = (int)(avail / (2ull * SS * sizeof(int)));  // labels + areas
  if (chunk > NM) chunk = NM;
  if (chunk < 1) return;  // insufficient workspace (would fail validation)

  int* labels = (int*)base;
  int* areas  = labels + (size_t)chunk * SS;

  k_meta_init<<<1, 128, 0, stream>>>(mt);
  for (int c0 = 0; c0 < NM; c0 += chunk) {
    int cn = (chunk < NM - c0) ? chunk : (NM - c0);
    int blocks = cn * (SS / 256);
    k_local  <<<cn * NT, 512, 0, stream>>>(in, c0, labels, areas, mt);
    k_seam   <<<cn * (NT - 1), 256, 0, stream>>>(labels);
    k_flatten<<<blocks, 256, 0, stream>>>(labels, areas);
    k_top2   <<<cn,    1024, 0, stream>>>(labels, areas, mt, c0);
    k_bbox   <<<cn * 16, 1024, 0, stream>>>(labels, mt, c0);
    k_inside <<<cn * 8, 256, 0, stream>>>(in, mt, c0);
  }
  k_final<<<1, 128, 0, stream>>>(mt, out);
}

// Round 6
// 262.621 us; speedup vs baseline: 11.6769x; 1.1485x over previous
//
#include <hip/hip_runtime.h>

#define HH 256
#define WW 256
#define SS 65536   // pixels per mask; also the background sentinel label
#define NM 128     // B*K masks
#define SPT 2048   // slots per tile = worst-case 8-conn components in 32x256
#define SPM 16384  // slots per mask (8 tiles)

struct Meta {
  double dsum[NM];   // total sum of m per mask
  double dins[NM];   // sum of m inside suppressed bbox
  int h0[NM]; int h1[NM]; int w0[NM]; int w1[NM];      // chosen bbox, inclusive
  int bh0[NM]; int bh1[NM]; int bw0[NM]; int bw1[NM];  // background bbox
  int fg0[NM];       // is mask pixel 0 foreground
};

__global__ void k_meta_init(Meta* mt) {
  int i = threadIdx.x;
  if (i < NM) {
    mt->dsum[i] = 0.0; mt->dins[i] = 0.0; mt->fg0[i] = 0;
    mt->h0[i] = 1; mt->h1[i] = 0; mt->w0[i] = 1; mt->w1[i] = 0;
    mt->bh0[i] = HH; mt->bh1[i] = -1; mt->bw0[i] = WW; mt->bw1[i] = -1;
  }
}

// Find with plain-store path compression (ECL-CC). Safe concurrent with
// atomicMin linking: stored values are live ancestors; parent < child.
__device__ __forceinline__ int find_c(int* L, int x) {
  int p = L[x];
  if (p == x) return x;
  int root = p, q = L[root];
  while (q != root) { root = q; q = L[root]; }
  if (root != p) L[x] = root;
  return root;
}

// Link larger root -> smaller root: final root = min id. Because compact-id
// order == root-pixel-label order, this preserves the reference's
// min-pixel-index component label.
__device__ void unite(int* L, int a, int b) {
  bool done = false;
  do {
    a = find_c(L, a);
    b = find_c(L, b);
    if (a < b)      { int old = atomicMin(&L[b], a); done = (old == b); b = old; }
    else if (b < a) { int old = atomicMin(&L[a], b); done = (old == a); a = old; }
    else done = true;
  } while (!done);
}

// Path-halving find (static tree; races only lose compression).
__device__ __forceinline__ int find_halve(int* L, int x) {
  int p = L[x];
  while (p != x) {
    int gp = L[p];
    if (gp == p) return p;
    L[x] = gp;
    x = p; p = gp;
  }
  return x;
}

__device__ __forceinline__ int cid(const unsigned long long* rm,
                                   const int* wpre, int p) {
  int w = p >> 6, b = p & 63;
  return wpre[w] + (int)__popcll(rm[w] & (b ? ((1ull << b) - 1) : 0ull));
}

// One block = one 32x256 tile. Full per-tile CCL in LDS + per-root stats
// (area, bbox) + compact record emission. No full-image label materialization.
// Pixel mapping p = tid + 512*j: wave's 64 lanes are 64 consecutive pixels ->
// conflict-free slab banking, ballot-based root enumeration.
__global__ __launch_bounds__(512)
void k_local(const float* __restrict__ in, int cb,
             int* __restrict__ gp, int* __restrict__ ga, int* __restrict__ gl,
             int* __restrict__ gh0, int* __restrict__ gh1,
             int* __restrict__ gw0, int* __restrict__ gw1,
             int* __restrict__ gbrow, int* __restrict__ gnr,
             Meta* __restrict__ mt) {
  __shared__ int slab[8192];                      // 32 KB
  __shared__ unsigned long long sfgw[32][4];      // fg row bitmasks
  __shared__ unsigned short sfg16[32][16];
  __shared__ unsigned long long rm[128];          // root bitmask (8192 bits)
  __shared__ int wpre[128];                       // word-exclusive root prefix
  __shared__ int snr;
  __shared__ int sA[SPT], sW0[SPT], sW1[SPT], sH0[SPT], sH1[SPT];  // 40 KB
  __shared__ double sred[8];
  __shared__ int sbb[4][8];

  int q = blockIdx.x, lm = q >> 3, tile = q & 7;
  int tid = threadIdx.x, lane = tid & 63, wv = tid >> 6;
  int gm = cb + lm, R0 = tile << 5;

  // P1: load input (contiguous 16 px/thread), m, dsum, fg bits (same order as
  // prior rounds -> bitwise-identical dsum).
  int r1 = tid >> 4, cs = tid & 15;
  const float4* src =
      (const float4*)(in + ((size_t)gm << 16) + ((R0 + r1) << 8) + (cs << 4));
  double dsum = 0.0;
  unsigned int fgb = 0;
  for (int k = 0; k < 4; k++) {
    float4 v = src[k];
    float m0 = fmaxf((v.x + 1.0f) * 0.5f, 0.0f);
    float m1 = fmaxf((v.y + 1.0f) * 0.5f, 0.0f);
    float m2 = fmaxf((v.z + 1.0f) * 0.5f, 0.0f);
    float m3 = fmaxf((v.w + 1.0f) * 0.5f, 0.0f);
    dsum += (double)m0 + (double)m1 + (double)m2 + (double)m3;
    fgb |= ((m0 > 0.5f) ? 1u : 0u) << (4 * k);
    fgb |= ((m1 > 0.5f) ? 1u : 0u) << (4 * k + 1);
    fgb |= ((m2 > 0.5f) ? 1u : 0u) << (4 * k + 2);
    fgb |= ((m3 > 0.5f) ? 1u : 0u) << (4 * k + 3);
  }
  sfg16[r1][cs] = (unsigned short)fgb;
  __syncthreads();
  if (cs < 4) {
    int b = cs * 4;
    sfgw[r1][cs] = (unsigned long long)sfg16[r1][b]
                 | ((unsigned long long)sfg16[r1][b + 1] << 16)
                 | ((unsigned long long)sfg16[r1][b + 2] << 32)
                 | ((unsigned long long)sfg16[r1][b + 3] << 48);
  }
  __syncthreads();

  // P2: slab init with run-start labels (clz on row bitmask).
  for (int j = 0; j < 16; j++) {
    int p = tid + (j << 9);
    int row = p >> 8, c = p & 255;
    const unsigned long long* Wr = sfgw[row];
    int lab = 0x7FFFFFFF;
    if ((Wr[c >> 6] >> (c & 63)) & 1) {
      int b = c & 63, w = c >> 6;
      unsigned long long z = ~Wr[w] & (b ? ((1ull << b) - 1) : 0ull);
      int w2 = w;
      while (z == 0 && w2 > 0) { w2--; z = ~Wr[w2]; }
      int start = z ? ((w2 << 6) + 63 - (int)__clzll(z) + 1) : 0;
      lab = (row << 8) + start;
    }
    slab[p] = lab;
  }
  __syncthreads();

  // P3: vertical unions with leftmost-contact dedup (all LDS).
  for (int j = 0; j < 16; j++) {
    int p = tid + (j << 9);
    int row = p >> 8, c = p & 255;
    if (row == 0) continue;
    const unsigned long long* Wr = sfgw[row];
    const unsigned long long* Wn = sfgw[row - 1];
    if (!((Wr[c >> 6] >> (c & 63)) & 1)) continue;
    bool wfg = (c > 0) && ((Wr[(c - 1) >> 6] >> ((c - 1) & 63)) & 1);
    bool nfg = (Wn[c >> 6] >> (c & 63)) & 1;
    if (!wfg) {
      if (nfg) unite(slab, p, p - 256);
      else if (c > 0 && ((Wn[(c - 1) >> 6] >> ((c - 1) & 63)) & 1))
        unite(slab, p, p - 257);
    }
    if (!nfg && c < 255 && ((Wn[(c + 1) >> 6] >> ((c + 1) & 63)) & 1))
      unite(slab, p, p - 255);
  }
  __syncthreads();

  // P4: resolve roots; ballot-built root bitmask (word == wave's 64 px).
  int rt[16];
  for (int j = 0; j < 16; j++) {
    int p = tid + (j << 9);
    int v = slab[p];
    int rr = -1;
    if (v != 0x7FFFFFFF) rr = find_halve(slab, p);
    rt[j] = rr;
    unsigned long long bal = __ballot(rr == p);
    if (lane == 0) rm[wv + (j << 3)] = bal;
  }
  __syncthreads();

  // Wave 0: exclusive word-prefix of root counts (compact ids in pixel order
  // -> global id order == label order). Other waves: init stats.
  if (tid < 64) {
    int pa = (int)__popcll(rm[tid]);
    int pb = (int)__popcll(rm[64 + tid]);
    int sa = pa, sb = pb;
    for (int off = 1; off < 64; off <<= 1) {
      int ta = __shfl_up(sa, off); if (tid >= off) sa += ta;
      int tb = __shfl_up(sb, off); if (tid >= off) sb += tb;
    }
    int totA = __shfl(sa, 63);
    int totB = __shfl(sb, 63);
    wpre[tid] = sa - pa;
    wpre[64 + tid] = totA + sb - pb;
    if (tid == 0) snr = totA + totB;
  } else {
    for (int s = tid - 64; s < SPT; s += 448) {
      sA[s] = 0; sW0[s] = WW; sW1[s] = -1; sH0[s] = 32; sH1[s] = -1;
    }
  }
  __syncthreads();

  // P5: per-root stats via wave-aggregated LDS atomics; bg bbox in registers.
  int bw0r = WW, bw1r = -1, bh0r = 32, bh1r = -1;
  for (int j = 0; j < 16; j++) {
    int p = tid + (j << 9);
    int row = p >> 8, c = p & 255;
    int rr = rt[j];
    if (rr < 0) {
      bw0r = min(bw0r, c); bw1r = max(bw1r, c);
      bh0r = min(bh0r, row); bh1r = max(bh1r, row);
    }
    int wc0 = c - lane;  // wave window base col (lanes are consecutive px)
    bool pend = rr >= 0;
    while (__any(pend)) {
      unsigned long long mk = __ballot(pend);
      int srcl = (int)__ffsll(mk) - 1;
      int lead = __shfl(rr, srcl);
      bool mine = pend && (rr == lead);
      unsigned long long grp = __ballot(mine);
      if (lane == srcl) {
        int id = cid(rm, wpre, lead);
        int lo = (int)__ffsll(grp) - 1;
        int hi = 63 - (int)__clzll(grp);
        atomicAdd(&sA[id], (int)__popcll(grp));
        atomicMin(&sW0[id], wc0 + lo);
        atomicMax(&sW1[id], wc0 + hi);
        atomicMin(&sH0[id], row);
        atomicMax(&sH1[id], row);
      }
      pend = pend && !mine;
    }
  }
  __syncthreads();

  // P6: emit compact root records + seam boundary maps.
  int base = q << 11;
  for (int j = 0; j < 16; j++) {
    int p = tid + (j << 9);
    int row = p >> 8, c = p & 255;
    int rr = rt[j];
    if (rr == p) {
      int id = cid(rm, wpre, p);
      int gid = base + id;
      gp[gid] = gid;
      ga[gid] = sA[id];
      gl[gid] = (tile << 13) + p;       // root's mask-pixel index (the label)
      gw0[gid] = sW0[id]; gw1[gid] = sW1[id];
      gh0[gid] = R0 + sH0[id]; gh1[gid] = R0 + sH1[id];
    }
    if (row == 0 || row == 31) {
      int bi = (q << 9) + ((row == 31) ? 256 : 0) + c;
      gbrow[bi] = (rr >= 0) ? (base + cid(rm, wpre, rr)) : -1;
    }
  }
  if (tid == 0) gnr[q] = snr;

  // bg bbox + dsum block reductions.
  for (int off = 32; off > 0; off >>= 1) {
    bw0r = min(bw0r, __shfl_down(bw0r, off));
    bw1r = max(bw1r, __shfl_down(bw1r, off));
    bh0r = min(bh0r, __shfl_down(bh0r, off));
    bh1r = max(bh1r, __shfl_down(bh1r, off));
  }
  if (lane == 0) { sbb[0][wv] = bw0r; sbb[1][wv] = bw1r;
                   sbb[2][wv] = bh0r; sbb[3][wv] = bh1r; }
  for (int off = 32; off > 0; off >>= 1) dsum += __shfl_down(dsum, off);
  if (lane == 0) sred[wv] = dsum;
  __syncthreads();
  if (tid == 0) {
    int a0 = sbb[0][0], a1 = sbb[1][0], a2 = sbb[2][0], a3 = sbb[3][0];
    for (int i = 1; i < 8; i++) {
      a0 = min(a0, sbb[0][i]); a1 = max(a1, sbb[1][i]);
      a2 = min(a2, sbb[2][i]); a3 = max(a3, sbb[3][i]);
    }
    if (a1 >= 0) {
      atomicMin(&mt->bw0[gm], a0); atomicMax(&mt->bw1[gm], a1);
      atomicMin(&mt->bh0[gm], R0 + a2); atomicMax(&mt->bh1[gm], R0 + a3);
    }
    double t = 0.0;
    for (int i = 0; i < 8; i++) t += sred[i];
    atomicAdd(&mt->dsum[gm], t);
    if (tile == 0) mt->fg0[gm] = (int)(sfgw[0][0] & 1ull);
  }
}

// Seam unions on compact ids via boundary maps (7 seams per mask).
__global__ void k_seam(int* __restrict__ gp, const int* __restrict__ gbrow) {
  int sidx = blockIdx.x;
  int lm = sidx / 7, s = sidx % 7;
  int tUp = (lm << 3) + s;
  const int* up = gbrow + (tUp << 9) + 256;       // bottom row of upper tile
  const int* lo = gbrow + ((tUp + 1) << 9);       // top row of lower tile
  int c = threadIdx.x;
  int v = lo[c];
  if (v < 0) return;
  bool wfg = (c > 0) && (lo[c - 1] >= 0);
  int n = up[c];
  if (!wfg) {
    if (n >= 0) unite(gp, v, n);
    else if (c > 0) { int nw = up[c - 1]; if (nw >= 0) unite(gp, v, nw); }
  }
  if (n < 0 && c < 255) { int ne = up[c + 1]; if (ne >= 0) unite(gp, v, ne); }
}

// Push non-root tile-root stats into their final root.
__global__ void k_stats(int* __restrict__ gp, int* __restrict__ ga,
                        int* __restrict__ gh0, int* __restrict__ gh1,
                        int* __restrict__ gw0, int* __restrict__ gw1,
                        const int* __restrict__ gnr) {
  int i = blockIdx.x * blockDim.x + threadIdx.x;
  int tile = i >> 11;
  if ((i & (SPT - 1)) >= gnr[tile]) return;
  int r = find_c(gp, i);
  if (r != i) {
    atomicAdd(&ga[r], ga[i]);
    atomicMin(&gh0[r], gh0[i]); atomicMax(&gh1[r], gh1[i]);
    atomicMin(&gw0[r], gw0[i]); atomicMax(&gw1[r], gw1[i]);
  }
}

// Per-mask top-2 over compact roots + exact lax.top_k candidate set
// (background label SS; zero-area label = fg(px0)?1:0), then bbox pick.
// key = (area<<37)|((SS-lab)<<20)|slot : lexicographic (area desc, lab asc);
// slot bits never decide order (labs distinct).
__global__ __launch_bounds__(1024)
void k_top2(const int* __restrict__ gp, const int* __restrict__ ga,
            const int* __restrict__ gl,
            const int* __restrict__ gh0, const int* __restrict__ gh1,
            const int* __restrict__ gw0, const int* __restrict__ gw1,
            const int* __restrict__ gnr, Meta* __restrict__ mt, int c0) {
  int lm = blockIdx.x, gm = c0 + lm;
  int tid = threadIdx.x;
  int sbase = lm << 14;
  unsigned long long t1 = 0, t2 = 0;
  int fsum = 0;
  for (int s = tid; s < SPM; s += 1024) {
    int tg = (lm << 3) + (s >> 11);
    if ((s & (SPT - 1)) < gnr[tg]) {
      int gid = sbase + s;
      if (gp[gid] == gid) {
        int a = ga[gid], lab = gl[gid];
        fsum += a;
        unsigned long long key = ((unsigned long long)a << 37)
                               | ((unsigned long long)(SS - lab) << 20)
                               | (unsigned)s;
        if (key > t1) { t2 = t1; t1 = key; }
        else if (key > t2) t2 = key;
      }
    }
  }
  for (int off = 32; off > 0; off >>= 1) {
    unsigned long long o1 = __shfl_down(t1, off), o2 = __shfl_down(t2, off);
    if (o1 > t1) { t2 = (t1 > o2) ? t1 : o2; t1 = o1; }
    else if (o1 > t2) t2 = o1;
    fsum += __shfl_down(fsum, off);
  }
  __shared__ unsigned long long s1[16], s2[16];
  __shared__ int sf[16];
  int wv = tid >> 6, lane = tid & 63;
  if (lane == 0) { s1[wv] = t1; s2[wv] = t2; sf[wv] = fsum; }
  __syncthreads();
  if (tid == 0) {
    t1 = s1[0]; t2 = s2[0]; fsum = sf[0];
    for (int i = 1; i < 16; i++) {
      unsigned long long o1 = s1[i], o2 = s2[i];
      if (o1 > t1) { t2 = (t1 > o2) ? t1 : o2; t1 = o1; }
      else if (o1 > t2) t2 = o1;
      fsum += sf[i];
    }
    unsigned long long bg = ((unsigned long long)(SS - fsum)) << 37;
    int zl = mt->fg0[gm] ? 1 : 0;
    unsigned long long zk = ((unsigned long long)(SS - zl)) << 20;
    if (bg > t1) { t2 = t1; t1 = bg; } else if (bg > t2) t2 = bg;
    if (zk > t1) { t2 = t1; t1 = zk; } else if (zk > t2) t2 = zk;
    int h0, h1, w0, w1;
    if (t2 == bg) {
      h0 = mt->bh0[gm]; h1 = mt->bh1[gm]; w0 = mt->bw0[gm]; w1 = mt->bw1[gm];
    } else if (t2 == zk) {
      h0 = 1; h1 = 0; w0 = 1; w1 = 0;   // empty bbox
    } else {
      int sl = (int)(t2 & 0xFFFFF);
      int gid = sbase + sl;
      h0 = gh0[gid]; h1 = gh1[gid]; w0 = gw0[gid]; w1 = gw1[gid];
    }
    mt->h0[gm] = h0; mt->h1[gm] = h1; mt->w0[gm] = w0; mt->w1[gm] = w1;
  }
}

// 8 blocks per mask over the bbox rows; double partials into dins.
__global__ void k_inside(const float* __restrict__ in, Meta* __restrict__ mt,
                         int c0) {
  int b = blockIdx.x;
  int lm = b >> 3, seg = b & 7;
  int gm = c0 + lm;
  int h0 = mt->h0[gm], h1 = mt->h1[gm], w0 = mt->w0[gm], w1 = mt->w1[gm];
  double acc = 0.0;
  if (h1 >= h0) {
    int cc = w0 + threadIdx.x;
    if (cc <= w1) {
      const float* base = in + ((size_t)gm << 16);
      for (int rr = h0 + seg; rr <= h1; rr += 8) {
        float x = base[(rr << 8) + cc];
        acc += (double)fmaxf((x + 1.0f) * 0.5f, 0.0f);
      }
    }
  }
  for (int off = 32; off > 0; off >>= 1) acc += __shfl_down(acc, off);
  __shared__ double sd[4];
  int wid = threadIdx.x >> 6, lane = threadIdx.x & 63;
  if (lane == 0) sd[wid] = acc;
  __syncthreads();
  if (threadIdx.x == 0) {
    double t = sd[0] + sd[1] + sd[2] + sd[3];
    if (t != 0.0) atomicAdd(&mt->dins[gm], t);
  }
}

__global__ void k_final(const Meta* __restrict__ mt, float* __restrict__ out) {
  __shared__ double sd[NM];
  int t = threadIdx.x;
  sd[t] = (mt->dsum[t] - mt->dins[t]) / (double)SS;
  __syncthreads();
  for (int off = 64; off > 0; off >>= 1) {
    if (t < off) sd[t] += sd[t + off];
    __syncthreads();
  }
  if (t == 0) out[0] = (float)(sd[0] / (double)NM);
}

extern "C" void kernel_launch(void* const* d_in, const int* in_sizes, int n_in,
                              void* d_out, int out_size, void* d_ws,
                              size_t ws_size, hipStream_t stream) {
  const float* in = (const float*)d_in[0];
  float* out = (float*)d_out;

  Meta* mt = (Meta*)d_ws;
  const size_t meta_bytes = (sizeof(Meta) + 255) & ~(size_t)255;
  char* base = (char*)d_ws + meta_bytes;
  size_t avail = (ws_size > meta_bytes) ? (ws_size - meta_bytes) : 0;
  // per-mask: 7 compact arrays x 16384 slots + boundary rows + nroots
  const size_t per_mask = (size_t)(7 * SPM + 8 * 512 + 8) * sizeof(int);
  int chunk = (int)(avail / per_mask);
  if (chunk > NM) chunk = NM;
  if (chunk < 1) return;  // insufficient workspace (would fail validation)

  int* gp    = (int*)base;
  int* ga    = gp  + (size_t)chunk * SPM;
  int* gl    = ga  + (size_t)chunk * SPM;
  int* gh0   = gl  + (size_t)chunk * SPM;
  int* gh1   = gh0 + (size_t)chunk * SPM;
  int* gw0   = gh1 + (size_t)chunk * SPM;
  int* gw1   = gw0 + (size_t)chunk * SPM;
  int* gbrow = gw1 + (size_t)chunk * SPM;
  int* gnr   = gbrow + (size_t)chunk * 4096;

  k_meta_init<<<1, 128, 0, stream>>>(mt);
  for (int c0 = 0; c0 < NM; c0 += chunk) {
    int cn = (chunk < NM - c0) ? chunk : (NM - c0);
    k_local<<<cn * 8, 512, 0, stream>>>(in, c0, gp, ga, gl, gh0, gh1, gw0,
                                        gw1, gbrow, gnr, mt);
    k_seam <<<cn * 7, 256, 0, stream>>>(gp, gbrow);
    k_stats<<<cn * 64, 256, 0, stream>>>(gp, ga, gh0, gh1, gw0, gw1, gnr);
    k_top2 <<<cn, 1024, 0, stream>>>(gp, ga, gl, gh0, gh1, gw0, gw1, gnr, mt,
                                     c0);
    k_inside<<<cn * 8, 256, 0, stream>>>(in, mt, c0);
  }
  k_final<<<1, 128, 0, stream>>>(mt, out);
}